// Round 9
// baseline (871.140 us; speedup 1.0000x reference)
//
#include <hip/hip_runtime.h>
#include <hip/hip_bf16.h>
#include <math.h>

constexpr int IN_F = 768;
constexpr float NEG_SLOPE = 0.2f;
constexpr float BN_EPS = 1e-5f;

typedef __attribute__((ext_vector_type(8))) short short8;
typedef __attribute__((ext_vector_type(4))) float f32x4;

__device__ inline float bf2f(unsigned short u) {
    unsigned int x = ((unsigned int)u) << 16;
    return __uint_as_float(x);
}
__device__ inline unsigned short f2bf(float f) {
    __hip_bfloat16 h = __float2bfloat16(f);
    return *(unsigned short*)&h;
}
__device__ inline void gload_lds16(const unsigned short* g, unsigned short* l) {
    __builtin_amdgcn_global_load_lds(
        (const __attribute__((address_space(1))) void*)g,
        (__attribute__((address_space(3))) void*)l, 16, 0, 0);
}

// ---------------- CSR build ----------------

__global__ void count_edges(const int* __restrict__ dst, int E, int* __restrict__ count) {
    int e = blockIdx.x * blockDim.x + threadIdx.x;
    if (e < E) atomicAdd(&count[dst[e]], 1);
}

// single-block scan, 16 elems/thread (counts already include self-loop via init=1)
__global__ void scan_counts(const int* __restrict__ count, int* __restrict__ row_start, int N) {
    __shared__ int wsum[17];
    __shared__ int carry;
    int tid = threadIdx.x;
    int lane = tid & 63, w = tid >> 6;
    if (tid == 0) carry = 0;
    __syncthreads();
    for (int base = 0; base < N; base += 16384) {
        int idx = base + tid * 16;
        int v[16];
        if (idx + 16 <= N) {
            #pragma unroll
            for (int j = 0; j < 4; j++) {
                int4 t4 = *(const int4*)&count[idx + j * 4];
                v[j * 4 + 0] = t4.x; v[j * 4 + 1] = t4.y;
                v[j * 4 + 2] = t4.z; v[j * 4 + 3] = t4.w;
            }
        } else {
            #pragma unroll
            for (int j = 0; j < 16; j++) v[j] = (idx + j < N) ? count[idx + j] : 0;
        }
        int tsum = 0;
        #pragma unroll
        for (int j = 0; j < 16; j++) tsum += v[j];
        int x = tsum;
        #pragma unroll
        for (int off = 1; off < 64; off <<= 1) {
            int y = __shfl_up(x, off, 64);
            if (lane >= off) x += y;
        }
        if (lane == 63) wsum[w] = x;
        __syncthreads();
        if (tid == 0) {
            int r = 0;
            for (int i = 0; i < 16; i++) { int t = wsum[i]; wsum[i] = r; r += t; }
            wsum[16] = r;
        }
        __syncthreads();
        int excl = carry + wsum[w] + (x - tsum);
        #pragma unroll
        for (int j = 0; j < 16; j++) {
            if (idx + j < N) row_start[idx + j] = excl;
            excl += v[j];
        }
        __syncthreads();
        if (tid == 0) carry += wsum[16];
        __syncthreads();
    }
    if (tid == 0) row_start[N] = carry;
}

__global__ void scatter_edges(const int* __restrict__ srcA, const int* __restrict__ dstA,
                              int E, int N, const int* __restrict__ row_start,
                              int* __restrict__ cursor, int* __restrict__ col) {
    int i = blockIdx.x * blockDim.x + threadIdx.x;
    if (i < E) {
        int d = dstA[i];
        int pos = row_start[d] + atomicAdd(&cursor[d], 1);
        col[pos] = srcA[i];
    } else if (i < E + N) {
        int n = i - E;
        int pos = row_start[n] + atomicAdd(&cursor[n], 1);
        col[pos] = n;
    }
}

// ---------------- cast: W -> Wt bf16 transposes + CSR count/cursor init ----------------

__global__ void cast_w(const float* __restrict__ W1, const float* __restrict__ W2,
                       const float* __restrict__ W3, unsigned short* __restrict__ Wt1,
                       unsigned short* __restrict__ Wt2, unsigned short* __restrict__ Wt3,
                       int* __restrict__ count, int* __restrict__ cursor, int N) {
    int j = blockIdx.x * blockDim.x + threadIdx.x;
    const int S1 = 768 * 512, S2 = 512 * 512, S3 = 512 * 128;
    if (j < S1) {
        int k = j / 512, n = j % 512;
        Wt1[(size_t)n * 768 + k] = f2bf(W1[j]);
    } else if (j < S1 + S2) {
        int jj = j - S1;
        int k = jj / 512, n = jj % 512;
        Wt2[(size_t)n * 512 + k] = f2bf(W2[jj]);
    } else if (j < S1 + S2 + S3) {
        int jj = j - S1 - S2;
        int k = jj / 128, n = jj % 128;
        Wt3[(size_t)n * 512 + k] = f2bf(W3[jj]);
    } else {
        int j2 = j - (S1 + S2 + S3);
        if (j2 < N) { count[j2] = 1; cursor[j2] = 0; }  // self-loop included
    }
}

// ---------------- bf16 MFMA GEMM + fused attention scores ----------------
// CAST_A=true: A is f32 (x). Depth-2 async-STAGE pipeline with the K-loop
// manually unrolled 2x so fa0/fa1 register buffers are STATICALLY indexed
// (rule #20: runtime-parity selection spills to scratch -- R8's 350MB WRITE).
// K must be a multiple of 128 (768 is). Bit-identical to a separate cast.
// CAST_A=false: A is bf16, async global_load_lds staging.
// Epilogue LDS-reduces the two wn-half scores and writes COMBINED s1/d1[N*H].

template <bool CAST_A>
__global__ __launch_bounds__(256, 3) void gemm_bf16(const unsigned short* __restrict__ A,
                                                    const float* __restrict__ Af,
                                                    const unsigned short* __restrict__ Wt,
                                                    unsigned short* __restrict__ C,
                                                    const float* __restrict__ a_s,
                                                    const float* __restrict__ a_d,
                                                    float* __restrict__ s1,
                                                    float* __restrict__ d1,
                                                    int M, int Nc, int K, int H) {
    __shared__ __align__(16) unsigned short As[128 * 64];
    __shared__ __align__(16) unsigned short Bs[128 * 64];
    const int tid = threadIdx.x;
    const int lane = tid & 63;
    const int wave = tid >> 6;
    const int wm = wave >> 1, wn = wave & 1;

    const int l = blockIdx.x;
    const int x = l & 7;
    const int t0 = l >> 3;
    const int HT = Nc >> 7;
    const int by = (HT == 4) ? (t0 & 3) : 0;
    const int g  = (HT == 4) ? (t0 >> 2) : t0;
    const int rb = g * 8 + x;
    const int row0 = rb * 128, col0 = by * 128;
    if (row0 >= M) return;

    f32x4 acc[4][4];
    #pragma unroll
    for (int i = 0; i < 4; i++)
        #pragma unroll
        for (int j = 0; j < 4; j++)
            acc[i][j] = (f32x4){0.f, 0.f, 0.f, 0.f};

    const int ldm = tid >> 3;
    const int kpart = (((tid & 7) ^ ((tid >> 3) & 7)) * 8);
    const int fr = lane & 15;
    const int quad = lane >> 4;

    // A-row source base (CAST_A): per-thread row pointer, row fixed across K
    const float* arow[4];
    if constexpr (CAST_A) {
        #pragma unroll
        for (int i = 0; i < 4; i++) {
            int gr = row0 + i * 32 + ldm; if (gr >= M) gr = M - 1;
            arow[i] = Af + (size_t)gr * K + kpart;
        }
    }

    #define LOAD_FA(dst, off)                                    \
        _Pragma("unroll")                                        \
        for (int i = 0; i < 4; i++) {                            \
            dst[i][0] = *(const float4*)(arow[i] + (off));       \
            dst[i][1] = *(const float4*)(arow[i] + (off) + 4);   \
        }
    #define CVT_WRITE(src)                                                                  \
        _Pragma("unroll")                                                                   \
        for (int i = 0; i < 4; i++) {                                                       \
            uint4 p;                                                                        \
            p.x = (unsigned int)f2bf(src[i][0].x) | ((unsigned int)f2bf(src[i][0].y) << 16);\
            p.y = (unsigned int)f2bf(src[i][0].z) | ((unsigned int)f2bf(src[i][0].w) << 16);\
            p.z = (unsigned int)f2bf(src[i][1].x) | ((unsigned int)f2bf(src[i][1].y) << 16);\
            p.w = (unsigned int)f2bf(src[i][1].z) | ((unsigned int)f2bf(src[i][1].w) << 16);\
            *(uint4*)&As[i * 2048 + tid * 8] = p;                                           \
        }
    #define GLOAD_B(k0v)                                                          \
        _Pragma("unroll")                                                         \
        for (int i = 0; i < 4; i++) {                                             \
            int n = col0 + i * 32 + ldm;                                          \
            gload_lds16(Wt + (size_t)n * K + (k0v) + kpart, &Bs[i * 2048 + tid * 8]); \
        }
    #define MFMA_PHASE                                                                   \
        _Pragma("unroll")                                                                \
        for (int s = 0; s < 2; s++) {                                                    \
            const int slot8 = (((s << 2) + quad) ^ (fr & 7)) * 8;                        \
            short8 a[4], b[4];                                                           \
            _Pragma("unroll")                                                            \
            for (int tt = 0; tt < 4; tt++) {                                             \
                a[tt] = *(const short8*)&As[(wm * 64 + tt * 16 + fr) * 64 + slot8];      \
                b[tt] = *(const short8*)&Bs[(wn * 64 + tt * 16 + fr) * 64 + slot8];      \
            }                                                                            \
            _Pragma("unroll")                                                            \
            for (int mi = 0; mi < 4; mi++)                                               \
                _Pragma("unroll")                                                        \
                for (int ni = 0; ni < 4; ni++)                                           \
                    acc[mi][ni] = __builtin_amdgcn_mfma_f32_16x16x32_bf16(               \
                        a[mi], b[ni], acc[mi][ni], 0, 0, 0);                             \
        }

    if constexpr (CAST_A) {
        // depth-2 prefetch, statically indexed via 2x-unrolled K loop (K % 128 == 0)
        float4 fa0[4][2], fa1[4][2];
        LOAD_FA(fa0, 0)
        LOAD_FA(fa1, 64)
        for (int k0 = 0; k0 < K; k0 += 128) {
            // ---- step A: K-step k0 (fa0) ----
            __syncthreads();
            GLOAD_B(k0)
            CVT_WRITE(fa0)
            __syncthreads();
            if (k0 + 128 < K) { LOAD_FA(fa0, k0 + 128) }   // in flight ~2 phases
            MFMA_PHASE
            // ---- step B: K-step k0+64 (fa1) ----
            __syncthreads();
            GLOAD_B(k0 + 64)
            CVT_WRITE(fa1)
            __syncthreads();
            if (k0 + 192 < K) { LOAD_FA(fa1, k0 + 192) }
            MFMA_PHASE
        }
    } else {
        for (int k0 = 0; k0 < K; k0 += 64) {
            __syncthreads();
            #pragma unroll
            for (int i = 0; i < 4; i++) {
                int gr = row0 + i * 32 + ldm; if (gr >= M) gr = M - 1;
                gload_lds16(A + (size_t)gr * K + k0 + kpart, &As[i * 2048 + tid * 8]);
                int n = col0 + i * 32 + ldm;
                gload_lds16(Wt + (size_t)n * K + k0 + kpart, &Bs[i * 2048 + tid * 8]);
            }
            __syncthreads();
            MFMA_PHASE
        }
    }

    #undef LOAD_FA
    #undef CVT_WRITE
    #undef GLOAD_B
    #undef MFMA_PHASE

    const int rbase = row0 + wm * 64 + quad * 4;
    const int cbase = col0 + wn * 64 + fr;
    #pragma unroll
    for (int mi = 0; mi < 4; mi++) {
        #pragma unroll
        for (int reg = 0; reg < 4; reg++) {
            int r = rbase + mi * 16 + reg;
            if (r < M) {
                #pragma unroll
                for (int ni = 0; ni < 4; ni++)
                    C[(size_t)r * Nc + cbase + ni * 16] = f2bf(acc[mi][ni][reg]);
            }
        }
    }

    float asv[4], adv[4];
    #pragma unroll
    for (int ni = 0; ni < 4; ni++) {
        int c = by * 128 + wn * 64 + ni * 16 + fr;
        asv[ni] = a_s[c];
        adv[ni] = a_d[c];
    }
    float ps[4][4], pd[4][4];
    #pragma unroll
    for (int mi = 0; mi < 4; mi++)
        #pragma unroll
        for (int reg = 0; reg < 4; reg++) {
            float t = 0.f, u = 0.f;
            #pragma unroll
            for (int ni = 0; ni < 4; ni++) {
                t += acc[mi][ni][reg] * asv[ni];
                u += acc[mi][ni][reg] * adv[ni];
            }
            ps[mi][reg] = t;
            pd[mi][reg] = u;
        }
    #pragma unroll
    for (int off = 1; off <= 8; off <<= 1)
        #pragma unroll
        for (int mi = 0; mi < 4; mi++)
            #pragma unroll
            for (int reg = 0; reg < 4; reg++) {
                ps[mi][reg] += __shfl_xor(ps[mi][reg], off, 64);
                pd[mi][reg] += __shfl_xor(pd[mi][reg], off, 64);
            }
    float oS = 0.f, oD = 0.f;
    #pragma unroll
    for (int mi = 0; mi < 4; mi++)
        #pragma unroll
        for (int reg = 0; reg < 4; reg++)
            if (fr == mi * 4 + reg) { oS = ps[mi][reg]; oD = pd[mi][reg]; }
    int rw = rbase + (fr >> 2) * 16 + (fr & 3);

    // cross-wave (wn) reduce of the two channel-halves via LDS; wn==0 stores combined
    __syncthreads();
    float* red = (float*)As;
    if (wn == 1) {
        red[wm * 64 + lane] = oS;
        red[128 + wm * 64 + lane] = oD;
    }
    __syncthreads();
    if (wn == 0) {
        float fS = oS + red[wm * 64 + lane];
        float fD = oD + red[128 + wm * 64 + lane];
        if (rw < M) {
            s1[(size_t)rw * H + by] = fS;
            d1[(size_t)rw * H + by] = fD;
        }
    }
}

// ---------------- H=4 aggregation: hoisted col/weights, readlane scalar h-bases ----------------

__global__ void gat_agg_h4(const unsigned short* __restrict__ h,
                           const float* __restrict__ s1, const float* __restrict__ d1,
                           const int* __restrict__ row_start, const int* __restrict__ col,
                           const float* __restrict__ bias,
                           const float* __restrict__ gam, const float* __restrict__ beta,
                           const float* __restrict__ rm, const float* __restrict__ rv,
                           unsigned short* __restrict__ out, int N) {
    __shared__ float wlds[4][4][64];
    int lane = threadIdx.x & 63;
    int wid = threadIdx.x >> 6;
    int n = blockIdx.x * 4 + wid;
    if (n >= N) return;
    n = __builtin_amdgcn_readfirstlane(n);
    int beg = __builtin_amdgcn_readfirstlane(row_start[n]);
    int end = __builtin_amdgcn_readfirstlane(row_start[n + 1]);
    int hh = lane >> 4;
    unsigned ch0 = (unsigned)lane * 8;
    float4 dh4 = *(const float4*)&d1[(size_t)n * 4];   // uniform

    float acc[8] = {0.f, 0.f, 0.f, 0.f, 0.f, 0.f, 0.f, 0.f};
    float denom = 0.f;

    for (int c0 = beg; c0 < end; c0 += 64) {
        int cnt = end - c0; if (cnt > 64) cnt = 64;
        int ce = c0 + (lane < cnt ? lane : cnt - 1);
        int cv = col[ce];                                   // one coalesced load
        float4 s4 = *(const float4*)&s1[(size_t)(unsigned)cv * 4];
        float live = (lane < cnt) ? 1.f : 0.f;
        float e0 = s4.x + dh4.x; e0 = e0 > 0.f ? e0 : NEG_SLOPE * e0;
        float e1 = s4.y + dh4.y; e1 = e1 > 0.f ? e1 : NEG_SLOPE * e1;
        float e2 = s4.z + dh4.z; e2 = e2 > 0.f ? e2 : NEG_SLOPE * e2;
        float e3 = s4.w + dh4.w; e3 = e3 > 0.f ? e3 : NEG_SLOPE * e3;
        wlds[wid][0][lane] = live * __expf(e0);
        wlds[wid][1][lane] = live * __expf(e1);
        wlds[wid][2][lane] = live * __expf(e2);
        wlds[wid][3][lane] = live * __expf(e3);
        // no barrier: wave-private LDS slice; compiler orders ds_write->ds_read

        int cend = c0 + cnt;
        for (int i = c0; i < cend; i += 8) {
            int base = i - c0;
            uint4 raw[8]; float w[8];
            #pragma unroll
            for (int u = 0; u < 8; u++) {
                int sn = __builtin_amdgcn_readlane(cv, base + u);   // SGPR, no wait
                w[u] = wlds[wid][hh][base + u];
                raw[u] = *(const uint4*)&h[((size_t)(unsigned)sn << 9) + ch0];
            }
            #pragma unroll
            for (int u = 0; u < 8; u++) {
                denom += w[u];
                acc[0] += w[u] * bf2f((unsigned short)(raw[u].x & 0xffff));
                acc[1] += w[u] * bf2f((unsigned short)(raw[u].x >> 16));
                acc[2] += w[u] * bf2f((unsigned short)(raw[u].y & 0xffff));
                acc[3] += w[u] * bf2f((unsigned short)(raw[u].y >> 16));
                acc[4] += w[u] * bf2f((unsigned short)(raw[u].z & 0xffff));
                acc[5] += w[u] * bf2f((unsigned short)(raw[u].z >> 16));
                acc[6] += w[u] * bf2f((unsigned short)(raw[u].w & 0xffff));
                acc[7] += w[u] * bf2f((unsigned short)(raw[u].w >> 16));
            }
        }
    }
    float inv = 1.f / denom;
    float v[8];
    #pragma unroll
    for (int c = 0; c < 8; c++) {
        int ch = ch0 + c;
        float t = acc[c] * inv + bias[ch];
        t = (t - rm[ch]) * (gam[ch] * rsqrtf(rv[ch] + BN_EPS)) + beta[ch];
        v[c] = t > 0.f ? t : expf(t) - 1.f;
    }
    uint4 p;
    p.x = (unsigned int)f2bf(v[0]) | ((unsigned int)f2bf(v[1]) << 16);
    p.y = (unsigned int)f2bf(v[2]) | ((unsigned int)f2bf(v[3]) << 16);
    p.z = (unsigned int)f2bf(v[4]) | ((unsigned int)f2bf(v[5]) << 16);
    p.w = (unsigned int)f2bf(v[6]) | ((unsigned int)f2bf(v[7]) << 16);
    *(uint4*)&out[((unsigned)n << 9) + ch0] = p;
}

// ---------------- H=1 aggregation + BN + ELU + fused classifier ----------------

__global__ void gat_agg_h1_cls(const unsigned short* __restrict__ h,
                               const float* __restrict__ s1, const float* __restrict__ d1,
                               const int* __restrict__ row_start, const int* __restrict__ col,
                               const float* __restrict__ bias,
                               const float* __restrict__ gam, const float* __restrict__ beta,
                               const float* __restrict__ rm, const float* __restrict__ rv,
                               const float* __restrict__ Wc, const float* __restrict__ bc,
                               float* __restrict__ out, int N) {
    int lane = threadIdx.x & 63;
    int wid = threadIdx.x >> 6;
    int n = blockIdx.x * 4 + wid;
    if (n >= N) return;
    n = __builtin_amdgcn_readfirstlane(n);
    int beg = __builtin_amdgcn_readfirstlane(row_start[n]);
    int end = __builtin_amdgcn_readfirstlane(row_start[n + 1]);
    int q = lane >> 4;
    int fl = lane & 15;
    const unsigned hoff = (unsigned)fl * 8;
    float dsum = d1[n];

    float acc[8] = {0.f, 0.f, 0.f, 0.f, 0.f, 0.f, 0.f, 0.f};
    float denom = 0.f;

    for (int c0 = beg; c0 < end; c0 += 64) {
        int cnt = end - c0; if (cnt > 64) cnt = 64;
        int ce = c0 + (lane < cnt ? lane : cnt - 1);
        int cv = col[ce];
        float ev = s1[(unsigned)cv] + dsum;
        ev = ev > 0.f ? ev : NEG_SLOPE * ev;
        float wv = (lane < cnt) ? __expf(ev) : 0.f;

        int cend = c0 + cnt;
        for (int i = c0; i < cend; i += 16) {
            int base = i - c0;
            uint4 raw[4]; float w[4];
            #pragma unroll
            for (int u = 0; u < 4; u++) {
                int urel = base + u * 4 + q;
                urel = urel < 63 ? urel : 63;
                int sn = __shfl(cv, urel, 64);
                w[u] = __shfl(wv, urel, 64);
                raw[u] = *(const uint4*)&h[((size_t)(unsigned)sn << 7) + hoff];
            }
            #pragma unroll
            for (int u = 0; u < 4; u++) {
                denom += w[u];
                acc[0] += w[u] * bf2f((unsigned short)(raw[u].x & 0xffff));
                acc[1] += w[u] * bf2f((unsigned short)(raw[u].x >> 16));
                acc[2] += w[u] * bf2f((unsigned short)(raw[u].y & 0xffff));
                acc[3] += w[u] * bf2f((unsigned short)(raw[u].y >> 16));
                acc[4] += w[u] * bf2f((unsigned short)(raw[u].z & 0xffff));
                acc[5] += w[u] * bf2f((unsigned short)(raw[u].z >> 16));
                acc[6] += w[u] * bf2f((unsigned short)(raw[u].w & 0xffff));
                acc[7] += w[u] * bf2f((unsigned short)(raw[u].w >> 16));
            }
        }
    }
    #pragma unroll
    for (int c = 0; c < 8; c++) {
        acc[c] += __shfl_xor(acc[c], 16, 64);
        acc[c] += __shfl_xor(acc[c], 32, 64);
    }
    denom += __shfl_xor(denom, 16, 64);
    denom += __shfl_xor(denom, 32, 64);

    if (q == 0) {
        float inv = 1.f / denom;
        int ch0 = fl * 8;
        float p0 = 0.f, p1 = 0.f;
        #pragma unroll
        for (int c = 0; c < 8; c++) {
            int ch = ch0 + c;
            float t = acc[c] * inv + bias[ch];
            t = (t - rm[ch]) * (gam[ch] * rsqrtf(rv[ch] + BN_EPS)) + beta[ch];
            t = t > 0.f ? t : expf(t) - 1.f;
            p0 += t * Wc[ch * 2 + 0];
            p1 += t * Wc[ch * 2 + 1];
        }
        #pragma unroll
        for (int off = 8; off >= 1; off >>= 1) {
            p0 += __shfl_xor(p0, off, 64);
            p1 += __shfl_xor(p1, off, 64);
        }
        if (fl == 0) {
            out[n * 2 + 0] = p0 + bc[0];
            out[n * 2 + 1] = p1 + bc[1];
        }
    }
}

// ---------------- launch ----------------

extern "C" void kernel_launch(void* const* d_in, const int* in_sizes, int n_in,
                              void* d_out, int out_size, void* d_ws, size_t ws_size,
                              hipStream_t stream) {
    const float* x   = (const float*)d_in[0];
    const int*   ei  = (const int*)d_in[1];
    const float* W1  = (const float*)d_in[2];
    const float* a1s = (const float*)d_in[3];
    const float* a1d = (const float*)d_in[4];
    const float* b1  = (const float*)d_in[5];
    const float* gm1 = (const float*)d_in[6];
    const float* be1 = (const float*)d_in[7];
    const float* rm1 = (const float*)d_in[8];
    const float* rv1 = (const float*)d_in[9];
    const float* W2  = (const float*)d_in[10];
    const float* a2s = (const float*)d_in[11];
    const float* a2d = (const float*)d_in[12];
    const float* b2  = (const float*)d_in[13];
    const float* gm2 = (const float*)d_in[14];
    const float* be2 = (const float*)d_in[15];
    const float* rm2 = (const float*)d_in[16];
    const float* rv2 = (const float*)d_in[17];
    const float* W3  = (const float*)d_in[18];
    const float* a3s = (const float*)d_in[19];
    const float* a3d = (const float*)d_in[20];
    const float* b3  = (const float*)d_in[21];
    const float* gm3 = (const float*)d_in[22];
    const float* be3 = (const float*)d_in[23];
    const float* rm3 = (const float*)d_in[24];
    const float* rv3 = (const float*)d_in[25];
    const float* Wc  = (const float*)d_in[26];
    const float* bc  = (const float*)d_in[27];

    int N = in_sizes[0] / IN_F;       // 50000
    int E = in_sizes[1] / 2;          // 400000
    int P = E + N;                    // CSR slots
    const int* srcA = ei;
    const int* dstA = ei + E;

    unsigned short* hbuf = (unsigned short*)d_ws;        // N*512 bf16
    unsigned short* gbuf = hbuf + (size_t)N * 512;       // N*512 bf16
    float* s1   = (float*)(gbuf + (size_t)N * 512);      // N*4 combined src scores
    float* d1   = s1 + (size_t)N * 4;                    // N*4 combined dst scores
    unsigned short* Wt1 = (unsigned short*)(d1 + (size_t)N * 4);   // 512*768
    unsigned short* Wt2 = Wt1 + 512 * 768;               // 512*512
    unsigned short* Wt3 = Wt2 + 512 * 512;               // 128*512
    int* count     = (int*)(Wt3 + 128 * 512);
    int* cursor    = count + N;
    int* row_start = cursor + N;
    int* col       = row_start + N + 1;                  // P

    // W transposes + CSR count/cursor init, one small launch
    int ctot = 768 * 512 + 512 * 512 + 512 * 128 + N;
    cast_w<<<(ctot + 255) / 256, 256, 0, stream>>>(W1, W2, W3, Wt1, Wt2, Wt3,
                                                   count, cursor, N);
    count_edges<<<(E + 255) / 256, 256, 0, stream>>>(dstA, E, count);
    scan_counts<<<1, 1024, 0, stream>>>(count, row_start, N);
    scatter_edges<<<(E + N + 255) / 256, 256, 0, stream>>>(srcA, dstA, E, N, row_start,
                                                           cursor, col);

    int Mb = (N + 127) / 128;          // 391
    int MbP = (Mb + 7) & ~7;           // 392, multiple of 8 for XCD mapping
    int Nb4 = (N + 3) / 4;

    // Layer 1 (A = f32 x, cast fused into depth-2 statically-unrolled pipeline)
    gemm_bf16<true><<<4 * MbP, 256, 0, stream>>>(nullptr, x, Wt1, hbuf, a1s, a1d,
                                                 s1, d1, N, 512, 768, 4);
    gat_agg_h4<<<Nb4, 256, 0, stream>>>(hbuf, s1, d1, row_start, col,
                                        b1, gm1, be1, rm1, rv1, gbuf, N);
    // Layer 2
    gemm_bf16<false><<<4 * MbP, 256, 0, stream>>>(gbuf, nullptr, Wt2, hbuf, a2s, a2d,
                                                  s1, d1, N, 512, 512, 4);
    gat_agg_h4<<<Nb4, 256, 0, stream>>>(hbuf, s1, d1, row_start, col,
                                        b2, gm2, be2, rm2, rv2, gbuf, N);
    // Layer 3 (1 head) + fused classifier
    gemm_bf16<false><<<MbP, 256, 0, stream>>>(gbuf, nullptr, Wt3, hbuf, a3s, a3d,
                                              s1, d1, N, 128, 512, 1);
    gat_agg_h1_cls<<<Nb4, 256, 0, stream>>>(hbuf, s1, d1, row_start, col,
                                            b3, gm3, be3, rm3, rv3, Wc, bc, (float*)d_out, N);
}

// Round 10
// 625.708 us; speedup vs baseline: 1.3922x; 1.3922x over previous
//
#include <hip/hip_runtime.h>
#include <hip/hip_bf16.h>
#include <math.h>

constexpr int IN_F = 768;
constexpr float NEG_SLOPE = 0.2f;
constexpr float BN_EPS = 1e-5f;

typedef __attribute__((ext_vector_type(8))) short short8;
typedef __attribute__((ext_vector_type(4))) float f32x4;

__device__ inline float bf2f(unsigned short u) {
    unsigned int x = ((unsigned int)u) << 16;
    return __uint_as_float(x);
}
__device__ inline unsigned short f2bf(float f) {
    __hip_bfloat16 h = __float2bfloat16(f);
    return *(unsigned short*)&h;
}
__device__ inline void gload_lds16(const unsigned short* g, unsigned short* l) {
    __builtin_amdgcn_global_load_lds(
        (const __attribute__((address_space(1))) void*)g,
        (__attribute__((address_space(3))) void*)l, 16, 0, 0);
}

// ---------------- CSR build ----------------

__global__ void count_edges(const int* __restrict__ dst, int E, int* __restrict__ count) {
    int e = blockIdx.x * blockDim.x + threadIdx.x;
    if (e < E) atomicAdd(&count[dst[e]], 1);
}

// single-block scan, 16 elems/thread (counts already include self-loop via init=1)
__global__ void scan_counts(const int* __restrict__ count, int* __restrict__ row_start, int N) {
    __shared__ int wsum[17];
    __shared__ int carry;
    int tid = threadIdx.x;
    int lane = tid & 63, w = tid >> 6;
    if (tid == 0) carry = 0;
    __syncthreads();
    for (int base = 0; base < N; base += 16384) {
        int idx = base + tid * 16;
        int v[16];
        if (idx + 16 <= N) {
            #pragma unroll
            for (int j = 0; j < 4; j++) {
                int4 t4 = *(const int4*)&count[idx + j * 4];
                v[j * 4 + 0] = t4.x; v[j * 4 + 1] = t4.y;
                v[j * 4 + 2] = t4.z; v[j * 4 + 3] = t4.w;
            }
        } else {
            #pragma unroll
            for (int j = 0; j < 16; j++) v[j] = (idx + j < N) ? count[idx + j] : 0;
        }
        int tsum = 0;
        #pragma unroll
        for (int j = 0; j < 16; j++) tsum += v[j];
        int x = tsum;
        #pragma unroll
        for (int off = 1; off < 64; off <<= 1) {
            int y = __shfl_up(x, off, 64);
            if (lane >= off) x += y;
        }
        if (lane == 63) wsum[w] = x;
        __syncthreads();
        if (tid == 0) {
            int r = 0;
            for (int i = 0; i < 16; i++) { int t = wsum[i]; wsum[i] = r; r += t; }
            wsum[16] = r;
        }
        __syncthreads();
        int excl = carry + wsum[w] + (x - tsum);
        #pragma unroll
        for (int j = 0; j < 16; j++) {
            if (idx + j < N) row_start[idx + j] = excl;
            excl += v[j];
        }
        __syncthreads();
        if (tid == 0) carry += wsum[16];
        __syncthreads();
    }
    if (tid == 0) row_start[N] = carry;
}

__global__ void scatter_edges(const int* __restrict__ srcA, const int* __restrict__ dstA,
                              int E, int N, const int* __restrict__ row_start,
                              int* __restrict__ cursor, int* __restrict__ col) {
    int i = blockIdx.x * blockDim.x + threadIdx.x;
    if (i < E) {
        int d = dstA[i];
        int pos = row_start[d] + atomicAdd(&cursor[d], 1);
        col[pos] = srcA[i];
    } else if (i < E + N) {
        int n = i - E;
        int pos = row_start[n] + atomicAdd(&cursor[n], 1);
        col[pos] = n;
    }
}

// ---------------- cast: W -> Wt bf16 transposes + CSR count/cursor init ----------------

__global__ void cast_w(const float* __restrict__ W1, const float* __restrict__ W2,
                       const float* __restrict__ W3, unsigned short* __restrict__ Wt1,
                       unsigned short* __restrict__ Wt2, unsigned short* __restrict__ Wt3,
                       int* __restrict__ count, int* __restrict__ cursor, int N) {
    int j = blockIdx.x * blockDim.x + threadIdx.x;
    const int S1 = 768 * 512, S2 = 512 * 512, S3 = 512 * 128;
    if (j < S1) {
        int k = j / 512, n = j % 512;
        Wt1[(size_t)n * 768 + k] = f2bf(W1[j]);
    } else if (j < S1 + S2) {
        int jj = j - S1;
        int k = jj / 512, n = jj % 512;
        Wt2[(size_t)n * 512 + k] = f2bf(W2[jj]);
    } else if (j < S1 + S2 + S3) {
        int jj = j - S1 - S2;
        int k = jj / 128, n = jj % 128;
        Wt3[(size_t)n * 512 + k] = f2bf(W3[jj]);
    } else {
        int j2 = j - (S1 + S2 + S3);
        if (j2 < N) { count[j2] = 1; cursor[j2] = 0; }  // self-loop included
    }
}

// ---------------- shared epilogue (C store + fused attention scores) ----------------

__device__ inline void gemm_epilogue(f32x4 (&acc)[4][4], unsigned short* C,
                                     const float* a_s, const float* a_d,
                                     float* s1, float* d1, unsigned short* AsLds,
                                     int M, int Nc, int H, int row0, int col0, int by,
                                     int wm, int wn, int lane, int fr, int quad) {
    const int rbase = row0 + wm * 64 + quad * 4;
    const int cbase = col0 + wn * 64 + fr;
    #pragma unroll
    for (int mi = 0; mi < 4; mi++) {
        #pragma unroll
        for (int reg = 0; reg < 4; reg++) {
            int r = rbase + mi * 16 + reg;
            if (r < M) {
                #pragma unroll
                for (int ni = 0; ni < 4; ni++)
                    C[(size_t)r * Nc + cbase + ni * 16] = f2bf(acc[mi][ni][reg]);
            }
        }
    }

    float asv[4], adv[4];
    #pragma unroll
    for (int ni = 0; ni < 4; ni++) {
        int c = by * 128 + wn * 64 + ni * 16 + fr;
        asv[ni] = a_s[c];
        adv[ni] = a_d[c];
    }
    float ps[4][4], pd[4][4];
    #pragma unroll
    for (int mi = 0; mi < 4; mi++)
        #pragma unroll
        for (int reg = 0; reg < 4; reg++) {
            float t = 0.f, u = 0.f;
            #pragma unroll
            for (int ni = 0; ni < 4; ni++) {
                t += acc[mi][ni][reg] * asv[ni];
                u += acc[mi][ni][reg] * adv[ni];
            }
            ps[mi][reg] = t;
            pd[mi][reg] = u;
        }
    #pragma unroll
    for (int off = 1; off <= 8; off <<= 1)
        #pragma unroll
        for (int mi = 0; mi < 4; mi++)
            #pragma unroll
            for (int reg = 0; reg < 4; reg++) {
                ps[mi][reg] += __shfl_xor(ps[mi][reg], off, 64);
                pd[mi][reg] += __shfl_xor(pd[mi][reg], off, 64);
            }
    float oS = 0.f, oD = 0.f;
    #pragma unroll
    for (int mi = 0; mi < 4; mi++)
        #pragma unroll
        for (int reg = 0; reg < 4; reg++)
            if (fr == mi * 4 + reg) { oS = ps[mi][reg]; oD = pd[mi][reg]; }
    int rw = rbase + (fr >> 2) * 16 + (fr & 3);

    __syncthreads();
    float* red = (float*)AsLds;
    if (wn == 1) {
        red[wm * 64 + lane] = oS;
        red[128 + wm * 64 + lane] = oD;
    }
    __syncthreads();
    if (wn == 0) {
        float fS = oS + red[wm * 64 + lane];
        float fD = oD + red[128 + wm * 64 + lane];
        if (rw < M) {
            s1[(size_t)rw * H + by] = fS;
            d1[(size_t)rw * H + by] = fD;
        }
    }
}

#define MFMA_PHASE                                                                   \
    _Pragma("unroll")                                                                \
    for (int s = 0; s < 2; s++) {                                                    \
        const int slot8 = (((s << 2) + quad) ^ (fr & 7)) * 8;                        \
        short8 a[4], b[4];                                                           \
        _Pragma("unroll")                                                            \
        for (int tt = 0; tt < 4; tt++) {                                             \
            a[tt] = *(const short8*)&As[(wm * 64 + tt * 16 + fr) * 64 + slot8];      \
            b[tt] = *(const short8*)&Bs[(wn * 64 + tt * 16 + fr) * 64 + slot8];      \
        }                                                                            \
        _Pragma("unroll")                                                            \
        for (int mi = 0; mi < 4; mi++)                                               \
            _Pragma("unroll")                                                        \
            for (int ni = 0; ni < 4; ni++)                                           \
                acc[mi][ni] = __builtin_amdgcn_mfma_f32_16x16x32_bf16(               \
                    a[mi], b[ni], acc[mi][ni], 0, 0, 0);                             \
    }

// ---------------- layer-1 GEMM: A = f32 x, depth-2 reg-prefetch cast ----------------
// Own kernel with __launch_bounds__(256, 2): ~256-VGPR budget so the 64 prefetch
// VGPRs stay live (R8/R9 at (256,3) spilled them to scratch: 350-535MB WRITE_SIZE).
// K=768, Nc=512, H=4 hardcoded. K-loop unrolled 2x -> fa0/fa1 statically indexed.

__global__ __launch_bounds__(256, 2) void gemm_cast1(const float* __restrict__ Af,
                                                     const unsigned short* __restrict__ Wt,
                                                     unsigned short* __restrict__ C,
                                                     const float* __restrict__ a_s,
                                                     const float* __restrict__ a_d,
                                                     float* __restrict__ s1,
                                                     float* __restrict__ d1, int M) {
    constexpr int K = 768, Nc = 512, H = 4;
    __shared__ __align__(16) unsigned short As[128 * 64];
    __shared__ __align__(16) unsigned short Bs[128 * 64];
    const int tid = threadIdx.x;
    const int lane = tid & 63;
    const int wave = tid >> 6;
    const int wm = wave >> 1, wn = wave & 1;

    const int l = blockIdx.x;
    const int x = l & 7;
    const int t0 = l >> 3;
    const int by = t0 & 3;
    const int g  = t0 >> 2;
    const int rb = g * 8 + x;
    const int row0 = rb * 128, col0 = by * 128;
    if (row0 >= M) return;

    f32x4 acc[4][4];
    #pragma unroll
    for (int i = 0; i < 4; i++)
        #pragma unroll
        for (int j = 0; j < 4; j++)
            acc[i][j] = (f32x4){0.f, 0.f, 0.f, 0.f};

    const int ldm = tid >> 3;
    const int kpart = (((tid & 7) ^ ((tid >> 3) & 7)) * 8);
    const int fr = lane & 15;
    const int quad = lane >> 4;

    const float* arow[4];
    #pragma unroll
    for (int i = 0; i < 4; i++) {
        int gr = row0 + i * 32 + ldm; if (gr >= M) gr = M - 1;
        arow[i] = Af + (size_t)gr * K + kpart;
    }

    #define LOAD_FA(dst, off)                                    \
        _Pragma("unroll")                                        \
        for (int i = 0; i < 4; i++) {                            \
            dst[i][0] = *(const float4*)(arow[i] + (off));       \
            dst[i][1] = *(const float4*)(arow[i] + (off) + 4);   \
        }
    #define CVT_WRITE(src)                                                                  \
        _Pragma("unroll")                                                                   \
        for (int i = 0; i < 4; i++) {                                                       \
            uint4 p;                                                                        \
            p.x = (unsigned int)f2bf(src[i][0].x) | ((unsigned int)f2bf(src[i][0].y) << 16);\
            p.y = (unsigned int)f2bf(src[i][0].z) | ((unsigned int)f2bf(src[i][0].w) << 16);\
            p.z = (unsigned int)f2bf(src[i][1].x) | ((unsigned int)f2bf(src[i][1].y) << 16);\
            p.w = (unsigned int)f2bf(src[i][1].z) | ((unsigned int)f2bf(src[i][1].w) << 16);\
            *(uint4*)&As[i * 2048 + tid * 8] = p;                                           \
        }
    #define GLOAD_B(k0v)                                                              \
        _Pragma("unroll")                                                             \
        for (int i = 0; i < 4; i++) {                                                 \
            int n = col0 + i * 32 + ldm;                                              \
            gload_lds16(Wt + (size_t)n * K + (k0v) + kpart, &Bs[i * 2048 + tid * 8]); \
        }

    float4 fa0[4][2], fa1[4][2];
    LOAD_FA(fa0, 0)
    LOAD_FA(fa1, 64)
    for (int k0 = 0; k0 < K; k0 += 128) {
        // ---- step A: K-step k0 (fa0) ----
        __syncthreads();
        GLOAD_B(k0)
        CVT_WRITE(fa0)
        __syncthreads();
        if (k0 + 128 < K) { LOAD_FA(fa0, k0 + 128) }   // in flight ~2 full phases
        MFMA_PHASE
        // ---- step B: K-step k0+64 (fa1) ----
        __syncthreads();
        GLOAD_B(k0 + 64)
        CVT_WRITE(fa1)
        __syncthreads();
        if (k0 + 192 < K) { LOAD_FA(fa1, k0 + 192) }
        MFMA_PHASE
    }
    #undef LOAD_FA
    #undef CVT_WRITE
    #undef GLOAD_B

    gemm_epilogue(acc, C, a_s, a_d, s1, d1, As, M, Nc, H,
                  row0, col0, by, wm, wn, lane, fr, quad);
}

// ---------------- layers 2/3 GEMM: bf16 A via global_load_lds (R7-exact) ----------------

__global__ __launch_bounds__(256, 3) void gemm_bf16(const unsigned short* __restrict__ A,
                                                    const unsigned short* __restrict__ Wt,
                                                    unsigned short* __restrict__ C,
                                                    const float* __restrict__ a_s,
                                                    const float* __restrict__ a_d,
                                                    float* __restrict__ s1,
                                                    float* __restrict__ d1,
                                                    int M, int Nc, int K, int H) {
    __shared__ __align__(16) unsigned short As[128 * 64];
    __shared__ __align__(16) unsigned short Bs[128 * 64];
    const int tid = threadIdx.x;
    const int lane = tid & 63;
    const int wave = tid >> 6;
    const int wm = wave >> 1, wn = wave & 1;

    const int l = blockIdx.x;
    const int x = l & 7;
    const int t0 = l >> 3;
    const int HT = Nc >> 7;
    const int by = (HT == 4) ? (t0 & 3) : 0;
    const int g  = (HT == 4) ? (t0 >> 2) : t0;
    const int rb = g * 8 + x;
    const int row0 = rb * 128, col0 = by * 128;
    if (row0 >= M) return;

    f32x4 acc[4][4];
    #pragma unroll
    for (int i = 0; i < 4; i++)
        #pragma unroll
        for (int j = 0; j < 4; j++)
            acc[i][j] = (f32x4){0.f, 0.f, 0.f, 0.f};

    const int ldm = tid >> 3;
    const int kpart = (((tid & 7) ^ ((tid >> 3) & 7)) * 8);
    const int fr = lane & 15;
    const int quad = lane >> 4;

    for (int k0 = 0; k0 < K; k0 += 64) {
        __syncthreads();
        #pragma unroll
        for (int i = 0; i < 4; i++) {
            int gr = row0 + i * 32 + ldm; if (gr >= M) gr = M - 1;
            gload_lds16(A + (size_t)gr * K + k0 + kpart, &As[i * 2048 + tid * 8]);
            int n = col0 + i * 32 + ldm;
            gload_lds16(Wt + (size_t)n * K + k0 + kpart, &Bs[i * 2048 + tid * 8]);
        }
        __syncthreads();
        MFMA_PHASE
    }

    gemm_epilogue(acc, C, a_s, a_d, s1, d1, As, M, Nc, H,
                  row0, col0, by, wm, wn, lane, fr, quad);
}

#undef MFMA_PHASE

// ---------------- H=4 aggregation: hoisted col/weights, readlane scalar h-bases ----------------

__global__ void gat_agg_h4(const unsigned short* __restrict__ h,
                           const float* __restrict__ s1, const float* __restrict__ d1,
                           const int* __restrict__ row_start, const int* __restrict__ col,
                           const float* __restrict__ bias,
                           const float* __restrict__ gam, const float* __restrict__ beta,
                           const float* __restrict__ rm, const float* __restrict__ rv,
                           unsigned short* __restrict__ out, int N) {
    __shared__ float wlds[4][4][64];
    int lane = threadIdx.x & 63;
    int wid = threadIdx.x >> 6;
    int n = blockIdx.x * 4 + wid;
    if (n >= N) return;
    n = __builtin_amdgcn_readfirstlane(n);
    int beg = __builtin_amdgcn_readfirstlane(row_start[n]);
    int end = __builtin_amdgcn_readfirstlane(row_start[n + 1]);
    int hh = lane >> 4;
    unsigned ch0 = (unsigned)lane * 8;
    float4 dh4 = *(const float4*)&d1[(size_t)n * 4];   // uniform

    float acc[8] = {0.f, 0.f, 0.f, 0.f, 0.f, 0.f, 0.f, 0.f};
    float denom = 0.f;

    for (int c0 = beg; c0 < end; c0 += 64) {
        int cnt = end - c0; if (cnt > 64) cnt = 64;
        int ce = c0 + (lane < cnt ? lane : cnt - 1);
        int cv = col[ce];                                   // one coalesced load
        float4 s4 = *(const float4*)&s1[(size_t)(unsigned)cv * 4];
        float live = (lane < cnt) ? 1.f : 0.f;
        float e0 = s4.x + dh4.x; e0 = e0 > 0.f ? e0 : NEG_SLOPE * e0;
        float e1 = s4.y + dh4.y; e1 = e1 > 0.f ? e1 : NEG_SLOPE * e1;
        float e2 = s4.z + dh4.z; e2 = e2 > 0.f ? e2 : NEG_SLOPE * e2;
        float e3 = s4.w + dh4.w; e3 = e3 > 0.f ? e3 : NEG_SLOPE * e3;
        wlds[wid][0][lane] = live * __expf(e0);
        wlds[wid][1][lane] = live * __expf(e1);
        wlds[wid][2][lane] = live * __expf(e2);
        wlds[wid][3][lane] = live * __expf(e3);
        // no barrier: wave-private LDS slice; compiler orders ds_write->ds_read

        int cend = c0 + cnt;
        for (int i = c0; i < cend; i += 8) {
            int base = i - c0;
            uint4 raw[8]; float w[8];
            #pragma unroll
            for (int u = 0; u < 8; u++) {
                int sn = __builtin_amdgcn_readlane(cv, base + u);   // SGPR, no wait
                w[u] = wlds[wid][hh][base + u];
                raw[u] = *(const uint4*)&h[((size_t)(unsigned)sn << 9) + ch0];
            }
            #pragma unroll
            for (int u = 0; u < 8; u++) {
                denom += w[u];
                acc[0] += w[u] * bf2f((unsigned short)(raw[u].x & 0xffff));
                acc[1] += w[u] * bf2f((unsigned short)(raw[u].x >> 16));
                acc[2] += w[u] * bf2f((unsigned short)(raw[u].y & 0xffff));
                acc[3] += w[u] * bf2f((unsigned short)(raw[u].y >> 16));
                acc[4] += w[u] * bf2f((unsigned short)(raw[u].z & 0xffff));
                acc[5] += w[u] * bf2f((unsigned short)(raw[u].z >> 16));
                acc[6] += w[u] * bf2f((unsigned short)(raw[u].w & 0xffff));
                acc[7] += w[u] * bf2f((unsigned short)(raw[u].w >> 16));
            }
        }
    }
    float inv = 1.f / denom;
    float v[8];
    #pragma unroll
    for (int c = 0; c < 8; c++) {
        int ch = ch0 + c;
        float t = acc[c] * inv + bias[ch];
        t = (t - rm[ch]) * (gam[ch] * rsqrtf(rv[ch] + BN_EPS)) + beta[ch];
        v[c] = t > 0.f ? t : expf(t) - 1.f;
    }
    uint4 p;
    p.x = (unsigned int)f2bf(v[0]) | ((unsigned int)f2bf(v[1]) << 16);
    p.y = (unsigned int)f2bf(v[2]) | ((unsigned int)f2bf(v[3]) << 16);
    p.z = (unsigned int)f2bf(v[4]) | ((unsigned int)f2bf(v[5]) << 16);
    p.w = (unsigned int)f2bf(v[6]) | ((unsigned int)f2bf(v[7]) << 16);
    *(uint4*)&out[((unsigned)n << 9) + ch0] = p;
}

// ---------------- H=1 aggregation + BN + ELU + fused classifier ----------------

__global__ void gat_agg_h1_cls(const unsigned short* __restrict__ h,
                               const float* __restrict__ s1, const float* __restrict__ d1,
                               const int* __restrict__ row_start, const int* __restrict__ col,
                               const float* __restrict__ bias,
                               const float* __restrict__ gam, const float* __restrict__ beta,
                               const float* __restrict__ rm, const float* __restrict__ rv,
                               const float* __restrict__ Wc, const float* __restrict__ bc,
                               float* __restrict__ out, int N) {
    int lane = threadIdx.x & 63;
    int wid = threadIdx.x >> 6;
    int n = blockIdx.x * 4 + wid;
    if (n >= N) return;
    n = __builtin_amdgcn_readfirstlane(n);
    int beg = __builtin_amdgcn_readfirstlane(row_start[n]);
    int end = __builtin_amdgcn_readfirstlane(row_start[n + 1]);
    int q = lane >> 4;
    int fl = lane & 15;
    const unsigned hoff = (unsigned)fl * 8;
    float dsum = d1[n];

    float acc[8] = {0.f, 0.f, 0.f, 0.f, 0.f, 0.f, 0.f, 0.f};
    float denom = 0.f;

    for (int c0 = beg; c0 < end; c0 += 64) {
        int cnt = end - c0; if (cnt > 64) cnt = 64;
        int ce = c0 + (lane < cnt ? lane : cnt - 1);
        int cv = col[ce];
        float ev = s1[(unsigned)cv] + dsum;
        ev = ev > 0.f ? ev : NEG_SLOPE * ev;
        float wv = (lane < cnt) ? __expf(ev) : 0.f;

        int cend = c0 + cnt;
        for (int i = c0; i < cend; i += 16) {
            int base = i - c0;
            uint4 raw[4]; float w[4];
            #pragma unroll
            for (int u = 0; u < 4; u++) {
                int urel = base + u * 4 + q;
                urel = urel < 63 ? urel : 63;
                int sn = __shfl(cv, urel, 64);
                w[u] = __shfl(wv, urel, 64);
                raw[u] = *(const uint4*)&h[((size_t)(unsigned)sn << 7) + hoff];
            }
            #pragma unroll
            for (int u = 0; u < 4; u++) {
                denom += w[u];
                acc[0] += w[u] * bf2f((unsigned short)(raw[u].x & 0xffff));
                acc[1] += w[u] * bf2f((unsigned short)(raw[u].x >> 16));
                acc[2] += w[u] * bf2f((unsigned short)(raw[u].y & 0xffff));
                acc[3] += w[u] * bf2f((unsigned short)(raw[u].y >> 16));
                acc[4] += w[u] * bf2f((unsigned short)(raw[u].z & 0xffff));
                acc[5] += w[u] * bf2f((unsigned short)(raw[u].z >> 16));
                acc[6] += w[u] * bf2f((unsigned short)(raw[u].w & 0xffff));
                acc[7] += w[u] * bf2f((unsigned short)(raw[u].w >> 16));
            }
        }
    }
    #pragma unroll
    for (int c = 0; c < 8; c++) {
        acc[c] += __shfl_xor(acc[c], 16, 64);
        acc[c] += __shfl_xor(acc[c], 32, 64);
    }
    denom += __shfl_xor(denom, 16, 64);
    denom += __shfl_xor(denom, 32, 64);

    if (q == 0) {
        float inv = 1.f / denom;
        int ch0 = fl * 8;
        float p0 = 0.f, p1 = 0.f;
        #pragma unroll
        for (int c = 0; c < 8; c++) {
            int ch = ch0 + c;
            float t = acc[c] * inv + bias[ch];
            t = (t - rm[ch]) * (gam[ch] * rsqrtf(rv[ch] + BN_EPS)) + beta[ch];
            t = t > 0.f ? t : expf(t) - 1.f;
            p0 += t * Wc[ch * 2 + 0];
            p1 += t * Wc[ch * 2 + 1];
        }
        #pragma unroll
        for (int off = 8; off >= 1; off >>= 1) {
            p0 += __shfl_xor(p0, off, 64);
            p1 += __shfl_xor(p1, off, 64);
        }
        if (fl == 0) {
            out[n * 2 + 0] = p0 + bc[0];
            out[n * 2 + 1] = p1 + bc[1];
        }
    }
}

// ---------------- launch ----------------

extern "C" void kernel_launch(void* const* d_in, const int* in_sizes, int n_in,
                              void* d_out, int out_size, void* d_ws, size_t ws_size,
                              hipStream_t stream) {
    const float* x   = (const float*)d_in[0];
    const int*   ei  = (const int*)d_in[1];
    const float* W1  = (const float*)d_in[2];
    const float* a1s = (const float*)d_in[3];
    const float* a1d = (const float*)d_in[4];
    const float* b1  = (const float*)d_in[5];
    const float* gm1 = (const float*)d_in[6];
    const float* be1 = (const float*)d_in[7];
    const float* rm1 = (const float*)d_in[8];
    const float* rv1 = (const float*)d_in[9];
    const float* W2  = (const float*)d_in[10];
    const float* a2s = (const float*)d_in[11];
    const float* a2d = (const float*)d_in[12];
    const float* b2  = (const float*)d_in[13];
    const float* gm2 = (const float*)d_in[14];
    const float* be2 = (const float*)d_in[15];
    const float* rm2 = (const float*)d_in[16];
    const float* rv2 = (const float*)d_in[17];
    const float* W3  = (const float*)d_in[18];
    const float* a3s = (const float*)d_in[19];
    const float* a3d = (const float*)d_in[20];
    const float* b3  = (const float*)d_in[21];
    const float* gm3 = (const float*)d_in[22];
    const float* be3 = (const float*)d_in[23];
    const float* rm3 = (const float*)d_in[24];
    const float* rv3 = (const float*)d_in[25];
    const float* Wc  = (const float*)d_in[26];
    const float* bc  = (const float*)d_in[27];

    int N = in_sizes[0] / IN_F;       // 50000
    int E = in_sizes[1] / 2;          // 400000
    int P = E + N;                    // CSR slots
    const int* srcA = ei;
    const int* dstA = ei + E;

    unsigned short* hbuf = (unsigned short*)d_ws;        // N*512 bf16
    unsigned short* gbuf = hbuf + (size_t)N * 512;       // N*512 bf16
    float* s1   = (float*)(gbuf + (size_t)N * 512);      // N*4 combined src scores
    float* d1   = s1 + (size_t)N * 4;                    // N*4 combined dst scores
    unsigned short* Wt1 = (unsigned short*)(d1 + (size_t)N * 4);   // 512*768
    unsigned short* Wt2 = Wt1 + 512 * 768;               // 512*512
    unsigned short* Wt3 = Wt2 + 512 * 512;               // 128*512
    int* count     = (int*)(Wt3 + 128 * 512);
    int* cursor    = count + N;
    int* row_start = cursor + N;
    int* col       = row_start + N + 1;                  // P

    // W transposes + CSR count/cursor init, one small launch
    int ctot = 768 * 512 + 512 * 512 + 512 * 128 + N;
    cast_w<<<(ctot + 255) / 256, 256, 0, stream>>>(W1, W2, W3, Wt1, Wt2, Wt3,
                                                   count, cursor, N);
    count_edges<<<(E + 255) / 256, 256, 0, stream>>>(dstA, E, count);
    scan_counts<<<1, 1024, 0, stream>>>(count, row_start, N);
    scatter_edges<<<(E + N + 255) / 256, 256, 0, stream>>>(srcA, dstA, E, N, row_start,
                                                           cursor, col);

    int Mb = (N + 127) / 128;          // 391
    int MbP = (Mb + 7) & ~7;           // 392, multiple of 8 for XCD mapping
    int Nb4 = (N + 3) / 4;

    // Layer 1 (A = f32 x, cast fused, dedicated kernel with 2-block bound)
    gemm_cast1<<<4 * MbP, 256, 0, stream>>>(x, Wt1, hbuf, a1s, a1d, s1, d1, N);
    gat_agg_h4<<<Nb4, 256, 0, stream>>>(hbuf, s1, d1, row_start, col,
                                        b1, gm1, be1, rm1, rv1, gbuf, N);
    // Layer 2
    gemm_bf16<<<4 * MbP, 256, 0, stream>>>(gbuf, Wt2, hbuf, a2s, a2d,
                                           s1, d1, N, 512, 512, 4);
    gat_agg_h4<<<Nb4, 256, 0, stream>>>(hbuf, s1, d1, row_start, col,
                                        b2, gm2, be2, rm2, rv2, gbuf, N);
    // Layer 3 (1 head) + fused classifier
    gemm_bf16<<<MbP, 256, 0, stream>>>(gbuf, Wt3, hbuf, a3s, a3d,
                                       s1, d1, N, 128, 512, 1);
    gat_agg_h1_cls<<<Nb4, 256, 0, stream>>>(hbuf, s1, d1, row_start, col,
                                            b3, gm3, be3, rm3, rv3, Wc, bc, (float*)d_out, N);
}